// Round 5
// baseline (139.793 us; speedup 1.0000x reference)
//
#include <hip/hip_runtime.h>
#include <hip/hip_bf16.h>
#include <math.h>

#define B_ 16
#define C_ 64
#define N_ 4096   // 64*64 pixels
#define M_ 1024   // 32*32 pooled keys

typedef __attribute__((ext_vector_type(8))) short v8s;   // 8 bf16 (4 VGPRs)
typedef __attribute__((ext_vector_type(4))) float v4f;   // 4 fp32 acc

__device__ inline unsigned short f2bf(float f) {
    __hip_bfloat16 h = __float2bfloat16(f);
    return *(unsigned short*)&h;
}
__device__ inline unsigned pack2bf(float a, float b) {
    return (unsigned)f2bf(a) | ((unsigned)f2bf(b) << 16);
}
__device__ inline v8s cvt8(float4 a, float4 b) {
    union { v8s v; unsigned u[4]; } r;
    r.u[0] = pack2bf(a.x, a.y);
    r.u[1] = pack2bf(a.z, a.w);
    r.u[2] = pack2bf(b.x, b.y);
    r.u[3] = pack2bf(b.z, b.w);
    return r.v;
}

// ---------------------------------------------------------------------------
// Kernel 1: MFMA conv (unchanged from round 4 — conv dropped 68 -> <10 us).
// Weights live in A-fragments loaded once; wave = one image row.
// ---------------------------------------------------------------------------
#define SPSTR 268   // sPool row stride (floats): 2-way banks

__global__ __launch_bounds__(256) void conv_pool_k(
    const float* __restrict__ x,
    const float* __restrict__ Wt, const float* __restrict__ bt,
    const float* __restrict__ Wp, const float* __restrict__ bp,
    const float* __restrict__ Wg, const float* __restrict__ bg,
    unsigned short* __restrict__ thetaT,
    unsigned short* __restrict__ phiT,
    unsigned short* __restrict__ gcm)
{
    __shared__ float sPool[40 * SPSTR];   // ch 0..7 = phi, 8..39 = g

    const int tid  = threadIdx.x;
    const int lane = tid & 63;
    const int wid  = tid >> 6;
    const int l15  = lane & 15;
    const int l4   = lane >> 4;

    const int b  = blockIdx.x >> 4;
    const int y0 = (blockIdx.x & 15) << 2;
    const int y  = y0 + wid;

    const float* row0 = (l15 < 8) ? (Wt + l15 * 64) : (Wp + (l15 - 8) * 64);
    const float* row1 = Wg + l15 * 64;
    const float* row2 = Wg + (16 + l15) * 64;
    v8s afrag[3][2];
    #pragma unroll
    for (int kh = 0; kh < 2; ++kh) {
        const int c0 = kh * 32 + l4 * 8;
        afrag[0][kh] = cvt8(*(const float4*)(row0 + c0), *(const float4*)(row0 + c0 + 4));
        afrag[1][kh] = cvt8(*(const float4*)(row1 + c0), *(const float4*)(row1 + c0 + 4));
        afrag[2][kh] = cvt8(*(const float4*)(row2 + c0), *(const float4*)(row2 + c0 + 4));
    }

    v4f acc[4][3];
    {
        float bv[3][4];
        #pragma unroll
        for (int r = 0; r < 4; ++r) {
            const int o = l4 * 4 + r;
            bv[0][r] = (o < 8) ? bt[o] : bp[o - 8];
            bv[1][r] = bg[o];
            bv[2][r] = bg[16 + o];
        }
        #pragma unroll
        for (int nt = 0; nt < 4; ++nt)
            #pragma unroll
            for (int t = 0; t < 3; ++t) {
                v4f a; a[0] = bv[t][0]; a[1] = bv[t][1];
                a[2] = bv[t][2]; a[3] = bv[t][3];
                acc[nt][t] = a;
            }
    }

    const float* xb = x + (size_t)b * C_ * N_ + y * 64;
    #pragma unroll
    for (int nt = 0; nt < 4; ++nt) {
        const int n0 = nt * 16 + l15;
        #pragma unroll
        for (int kh = 0; kh < 2; ++kh) {
            const int cb = kh * 32 + l4 * 8;
            float f[8];
            #pragma unroll
            for (int j = 0; j < 8; ++j) f[j] = xb[(size_t)(cb + j) * N_ + n0];
            union { v8s v; unsigned u[4]; } bf;
            #pragma unroll
            for (int j = 0; j < 4; ++j) bf.u[j] = pack2bf(f[2*j], f[2*j+1]);
            #pragma unroll
            for (int t = 0; t < 3; ++t)
                acc[nt][t] = __builtin_amdgcn_mfma_f32_16x16x32_bf16(
                    afrag[t][kh], bf.v, acc[nt][t], 0, 0, 0);
        }
    }

    #pragma unroll
    for (int nt = 0; nt < 4; ++nt) {
        if (l4 < 2) {
            const int n = y * 64 + nt * 16 + l15;
            const unsigned lo = pack2bf(acc[nt][0][0], acc[nt][0][1]);
            const unsigned hi = pack2bf(acc[nt][0][2], acc[nt][0][3]);
            *(uint2*)(thetaT + ((size_t)b * N_ + n) * 8 + l4 * 4) = make_uint2(lo, hi);
        }
    }

    #pragma unroll
    for (int nt = 0; nt < 4; ++nt) {
        const int px = wid * 64 + nt * 16 + l15;
        if (l4 >= 2) {
            #pragma unroll
            for (int r = 0; r < 4; ++r)
                sPool[((l4 - 2) * 4 + r) * SPSTR + px] = acc[nt][0][r];
        }
        #pragma unroll
        for (int r = 0; r < 4; ++r) {
            sPool[(8  + l4 * 4 + r) * SPSTR + px] = acc[nt][1][r];
            sPool[(24 + l4 * 4 + r) * SPSTR + px] = acc[nt][2][r];
        }
    }
    __syncthreads();

    {
        const int pm  = tid & 63, grp = tid >> 6;
        const int pr  = pm >> 5, pc = pm & 31;
        const int p00 = pr * 128 + pc * 2;
        const int mg  = ((y0 >> 1) + pr) * 32 + pc;
        #pragma unroll
        for (int i = 0; i < 10; ++i) {
            const int ch = grp * 10 + i;
            const float* sp = sPool + ch * SPSTR;
            const float v = fmaxf(fmaxf(sp[p00], sp[p00 + 1]),
                                  fmaxf(sp[p00 + 64], sp[p00 + 65]));
            if (ch < 8) phiT[((size_t)b * M_ + mg) * 8 + ch] = f2bf(v);
            else        gcm[((size_t)(b * 32 + ch - 8)) * M_ + mg] = f2bf(v);
        }
    }
}

// ---------------------------------------------------------------------------
// Kernel 2 (round 5): MFMA flash attention, restructured for latency hiding.
// Wave owns 16 queries (was 32) -> 4096 waves = 4/SIMD (was 2); grid 1024.
// Register-prefetch pipelining: tile t+1's global loads are issued right
// after the post-staging barrier so they fly during tile t's compute.
// LDS ~34 KB -> 4 blocks/CU (launch_bounds(256,4)).
// MFMA layouts (measured m89/m91): A[m=l15][k=l4*8+j], B[k=l4*8+j][n=l15],
// C/D: col(n)=l15, row(m)=l4*4+reg.
// ---------------------------------------------------------------------------
#define GPAD   264   // sgT row stride (shorts): 2-way banks (free)
#define PROW   40    // sP row stride (shorts): 80 B, 16B-aligned
#define SOSTR  65    // sO row stride (floats): odd -> scattered banks

__global__ __launch_bounds__(256, 4) void attn_k(
    const float* __restrict__ x,
    const unsigned short* __restrict__ thetaT,
    const unsigned short* __restrict__ phiT,
    const unsigned short* __restrict__ gcm,
    const float* __restrict__ Wo, const float* __restrict__ bo,
    const float* __restrict__ gammap,
    float* __restrict__ out)
{
    __shared__ unsigned short sphi[2][128][8];   // 4 KB   even/odd key split
    __shared__ unsigned short sgT[32][GPAD];     // 16.5 KB [c][m-chunk]
    __shared__ unsigned short sP[4][16][PROW];   // 5.1 KB  per-wave P slabs
    __shared__ float sO[32][SOSTR];              // 8.3 KB  [c][q] epilogue

    const int tid  = threadIdx.x;
    const int lane = tid & 63;
    const int wid  = tid >> 6;
    const int l15  = lane & 15;
    const int l4   = lane >> 4;

    const int b  = blockIdx.x >> 6;          // 64 blocks per batch
    const int q0 = (blockIdx.x & 63) << 6;   // 64 queries per block
    const int qw = q0 + wid * 16;            // this wave's 16 queries

    // theta A-fragment (K=8 real, rest zero): lanes 16..63 zero
    v8s aT;
    {
        v8s z = {};
        aT = z;
        if (l4 == 0)
            aT = *(const v8s*)(thetaT + ((size_t)b * N_ + qw + l15) * 8);
    }

    v4f accO[2];
    { v4f z = {}; accO[0] = z; accO[1] = z; }
    float lsum[4] = {0.f, 0.f, 0.f, 0.f};
    const v4f zf = {};

    const unsigned short* phb = phiT + (size_t)b * M_ * 8;
    const unsigned short* gb  = gcm  + (size_t)(b * 32) * M_;
    const int grow = tid >> 3, gch = tid & 7;

    // prefetch tile 0 into registers
    uint4 pf_phi = *(const uint4*)(phb + (size_t)(0 * 256 + tid) * 8);
    uint4 pf_g[4];
    {
        const uint4* gs = (const uint4*)(gb + (size_t)grow * M_ + 0 * 256 + gch * 32);
        pf_g[0] = gs[0]; pf_g[1] = gs[1]; pf_g[2] = gs[2]; pf_g[3] = gs[3];
    }

    for (int t = 0; t < 4; ++t) {            // 4 key tiles of 256
        // stage prefetched tile to LDS
        *(uint4*)&sphi[tid & 1][tid >> 1][0] = pf_phi;
        {
            uint4* gd = (uint4*)&sgT[grow][gch * 32];
            gd[0] = pf_g[0]; gd[1] = pf_g[1]; gd[2] = pf_g[2]; gd[3] = pf_g[3];
        }
        __syncthreads();

        // issue next tile's loads now — in flight during compute
        if (t < 3) {
            pf_phi = *(const uint4*)(phb + (size_t)((t + 1) * 256 + tid) * 8);
            const uint4* gs = (const uint4*)(gb + (size_t)grow * M_ + (t + 1) * 256 + gch * 32);
            pf_g[0] = gs[0]; pf_g[1] = gs[1]; pf_g[2] = gs[2]; pf_g[3] = gs[3];
        }

        #pragma unroll
        for (int cc = 0; cc < 8; ++cc) {     // 32-key chunks
            v8s bph0, bph1;
            { v8s z = {}; bph0 = z; bph1 = z; }
            if (l4 == 0) {
                bph0 = *(const v8s*)&sphi[0][cc * 16 + l15][0];
                bph1 = *(const v8s*)&sphi[1][cc * 16 + l15][0];
            }
            v4f s0 = __builtin_amdgcn_mfma_f32_16x16x32_bf16(aT, bph0, zf, 0, 0, 0);
            v4f s1 = __builtin_amdgcn_mfma_f32_16x16x32_bf16(aT, bph1, zf, 0, 0, 0);
            #pragma unroll
            for (int r = 0; r < 4; ++r) {
                float e0 = __expf(s0[r]);    // key cc*32 + 2*l15
                float e1 = __expf(s1[r]);    // key cc*32 + 2*l15 + 1
                lsum[r] += e0 + e1;
                *(unsigned*)&sP[wid][l4 * 4 + r][2 * l15] = pack2bf(e0, e1);
            }
            v8s bg0 = *(const v8s*)&sgT[l15     ][cc * 32 + l4 * 8];
            v8s bg1 = *(const v8s*)&sgT[16 + l15][cc * 32 + l4 * 8];
            v8s ap  = *(const v8s*)&sP[wid][l15][l4 * 8];
            accO[0] = __builtin_amdgcn_mfma_f32_16x16x32_bf16(ap, bg0, accO[0], 0, 0, 0);
            accO[1] = __builtin_amdgcn_mfma_f32_16x16x32_bf16(ap, bg1, accO[1], 0, 0, 0);
        }
        __syncthreads();
    }

    // softmax denominators: reduce across the 16 key-columns (lane&15)
    float rl[4];
    #pragma unroll
    for (int r = 0; r < 4; ++r) {
        float v = lsum[r];
        v += __shfl_xor(v, 1);
        v += __shfl_xor(v, 2);
        v += __shfl_xor(v, 4);
        v += __shfl_xor(v, 8);
        rl[r] = 1.0f / v;
    }

    // write normalized O to LDS [c][q_local]
    #pragma unroll
    for (int ct = 0; ct < 2; ++ct)
        #pragma unroll
        for (int r = 0; r < 4; ++r)
            sO[ct * 16 + l15][wid * 16 + l4 * 4 + r] = accO[ct][r] * rl[r];
    __syncthreads();

    // epilogue: out = gamma*(Wo . O + bo) + x. 256 thr = 64 q x 4 oc-quarters.
    {
        const int qq   = tid & 63;
        const int quad = tid >> 6;          // oc 16*quad .. 16*quad+15
        const int n    = q0 + qq;
        float col[32];
        #pragma unroll
        for (int c = 0; c < 32; ++c) col[c] = sO[c][qq];
        const float gamma = *gammap;
        const float* xb = x   + ((size_t)(b * 64 + quad * 16)) * N_ + n;
        float*       ob = out + ((size_t)(b * 64 + quad * 16)) * N_ + n;
        #pragma unroll
        for (int j = 0; j < 16; ++j) {
            const int oc = quad * 16 + j;
            const float* w = Wo + oc * 32;   // wave-uniform -> s_load
            float r = 0.f;
            #pragma unroll
            for (int c = 0; c < 32; ++c) r = fmaf(w[c], col[c], r);
            ob[(size_t)j * N_] = gamma * (r + bo[oc]) + xb[(size_t)j * N_];
        }
    }
}

// ---------------------------------------------------------------------------
extern "C" void kernel_launch(void* const* d_in, const int* in_sizes, int n_in,
                              void* d_out, int out_size, void* d_ws, size_t ws_size,
                              hipStream_t stream) {
    const float* x  = (const float*)d_in[0];
    const float* Wt = (const float*)d_in[1];
    const float* bt = (const float*)d_in[2];
    const float* Wp = (const float*)d_in[3];
    const float* bp = (const float*)d_in[4];
    const float* Wg = (const float*)d_in[5];
    const float* bg = (const float*)d_in[6];
    const float* Wo = (const float*)d_in[7];
    const float* bo = (const float*)d_in[8];
    const float* gm = (const float*)d_in[9];
    float* out = (float*)d_out;

    // workspace (bf16): thetaT [16][4096][8] | phiT [16][1024][8] | gcm [16][32][1024]
    unsigned short* thetaT = (unsigned short*)d_ws;
    unsigned short* phiT   = thetaT + (size_t)B_ * N_ * 8;
    unsigned short* gcm    = phiT   + (size_t)B_ * M_ * 8;

    hipLaunchKernelGGL(conv_pool_k, dim3(256), dim3(256), 0, stream,
                       x, Wt, bt, Wp, bp, Wg, bg, thetaT, phiT, gcm);
    hipLaunchKernelGGL(attn_k, dim3(1024), dim3(256), 0, stream,
                       x, thetaT, phiT, gcm, Wo, bo, gm, out);
}

// Round 6
// 123.536 us; speedup vs baseline: 1.1316x; 1.1316x over previous
//
#include <hip/hip_runtime.h>
#include <hip/hip_bf16.h>
#include <math.h>

#define B_ 16
#define C_ 64
#define N_ 4096   // 64*64 pixels
#define M_ 1024   // 32*32 pooled keys

typedef __attribute__((ext_vector_type(8))) short v8s;   // 8 bf16 (4 VGPRs)
typedef __attribute__((ext_vector_type(4))) float v4f;   // 4 fp32 acc

__device__ inline unsigned short f2bf(float f) {
    __hip_bfloat16 h = __float2bfloat16(f);
    return *(unsigned short*)&h;
}
__device__ inline unsigned pack2bf(float a, float b) {
    return (unsigned)f2bf(a) | ((unsigned)f2bf(b) << 16);
}
__device__ inline v8s cvt8(float4 a, float4 b) {
    union { v8s v; unsigned u[4]; } r;
    r.u[0] = pack2bf(a.x, a.y);
    r.u[1] = pack2bf(a.z, a.w);
    r.u[2] = pack2bf(b.x, b.y);
    r.u[3] = pack2bf(b.z, b.w);
    return r.v;
}

// ---------------------------------------------------------------------------
// Kernel 1: MFMA conv (unchanged since round 4 — weights in A-fragments
// loaded once; wave = one image row; phi/g pooled via LDS epilogue).
// ---------------------------------------------------------------------------
#define SPSTR 268   // sPool row stride (floats): 2-way banks

__global__ __launch_bounds__(256) void conv_pool_k(
    const float* __restrict__ x,
    const float* __restrict__ Wt, const float* __restrict__ bt,
    const float* __restrict__ Wp, const float* __restrict__ bp,
    const float* __restrict__ Wg, const float* __restrict__ bg,
    unsigned short* __restrict__ thetaT,
    unsigned short* __restrict__ phiT,
    unsigned short* __restrict__ gcm)
{
    __shared__ float sPool[40 * SPSTR];   // ch 0..7 = phi, 8..39 = g

    const int tid  = threadIdx.x;
    const int lane = tid & 63;
    const int wid  = tid >> 6;
    const int l15  = lane & 15;
    const int l4   = lane >> 4;

    const int b  = blockIdx.x >> 4;
    const int y0 = (blockIdx.x & 15) << 2;
    const int y  = y0 + wid;

    const float* row0 = (l15 < 8) ? (Wt + l15 * 64) : (Wp + (l15 - 8) * 64);
    const float* row1 = Wg + l15 * 64;
    const float* row2 = Wg + (16 + l15) * 64;
    v8s afrag[3][2];
    #pragma unroll
    for (int kh = 0; kh < 2; ++kh) {
        const int c0 = kh * 32 + l4 * 8;
        afrag[0][kh] = cvt8(*(const float4*)(row0 + c0), *(const float4*)(row0 + c0 + 4));
        afrag[1][kh] = cvt8(*(const float4*)(row1 + c0), *(const float4*)(row1 + c0 + 4));
        afrag[2][kh] = cvt8(*(const float4*)(row2 + c0), *(const float4*)(row2 + c0 + 4));
    }

    v4f acc[4][3];
    {
        float bv[3][4];
        #pragma unroll
        for (int r = 0; r < 4; ++r) {
            const int o = l4 * 4 + r;
            bv[0][r] = (o < 8) ? bt[o] : bp[o - 8];
            bv[1][r] = bg[o];
            bv[2][r] = bg[16 + o];
        }
        #pragma unroll
        for (int nt = 0; nt < 4; ++nt)
            #pragma unroll
            for (int t = 0; t < 3; ++t) {
                v4f a; a[0] = bv[t][0]; a[1] = bv[t][1];
                a[2] = bv[t][2]; a[3] = bv[t][3];
                acc[nt][t] = a;
            }
    }

    const float* xb = x + (size_t)b * C_ * N_ + y * 64;
    #pragma unroll
    for (int nt = 0; nt < 4; ++nt) {
        const int n0 = nt * 16 + l15;
        #pragma unroll
        for (int kh = 0; kh < 2; ++kh) {
            const int cb = kh * 32 + l4 * 8;
            float f[8];
            #pragma unroll
            for (int j = 0; j < 8; ++j) f[j] = xb[(size_t)(cb + j) * N_ + n0];
            union { v8s v; unsigned u[4]; } bf;
            #pragma unroll
            for (int j = 0; j < 4; ++j) bf.u[j] = pack2bf(f[2*j], f[2*j+1]);
            #pragma unroll
            for (int t = 0; t < 3; ++t)
                acc[nt][t] = __builtin_amdgcn_mfma_f32_16x16x32_bf16(
                    afrag[t][kh], bf.v, acc[nt][t], 0, 0, 0);
        }
    }

    #pragma unroll
    for (int nt = 0; nt < 4; ++nt) {
        if (l4 < 2) {
            const int n = y * 64 + nt * 16 + l15;
            const unsigned lo = pack2bf(acc[nt][0][0], acc[nt][0][1]);
            const unsigned hi = pack2bf(acc[nt][0][2], acc[nt][0][3]);
            *(uint2*)(thetaT + ((size_t)b * N_ + n) * 8 + l4 * 4) = make_uint2(lo, hi);
        }
    }

    #pragma unroll
    for (int nt = 0; nt < 4; ++nt) {
        const int px = wid * 64 + nt * 16 + l15;
        if (l4 >= 2) {
            #pragma unroll
            for (int r = 0; r < 4; ++r)
                sPool[((l4 - 2) * 4 + r) * SPSTR + px] = acc[nt][0][r];
        }
        #pragma unroll
        for (int r = 0; r < 4; ++r) {
            sPool[(8  + l4 * 4 + r) * SPSTR + px] = acc[nt][1][r];
            sPool[(24 + l4 * 4 + r) * SPSTR + px] = acc[nt][2][r];
        }
    }
    __syncthreads();

    {
        const int pm  = tid & 63, grp = tid >> 6;
        const int pr  = pm >> 5, pc = pm & 31;
        const int p00 = pr * 128 + pc * 2;
        const int mg  = ((y0 >> 1) + pr) * 32 + pc;
        #pragma unroll
        for (int i = 0; i < 10; ++i) {
            const int ch = grp * 10 + i;
            const float* sp = sPool + ch * SPSTR;
            const float v = fmaxf(fmaxf(sp[p00], sp[p00 + 1]),
                                  fmaxf(sp[p00 + 64], sp[p00 + 65]));
            if (ch < 8) phiT[((size_t)b * M_ + mg) * 8 + ch] = f2bf(v);
            else        gcm[((size_t)(b * 32 + ch - 8)) * M_ + mg] = f2bf(v);
        }
    }
}

// ---------------------------------------------------------------------------
// Kernel 2 (round 6): MFMA flash attention. Keeps round-5's occupancy win
// (16 q/wave, 4096 waves = 4/SIMD via LDS 34.8KB -> 4 blocks/CU) but removes
// what caused the round-5 spill regression (WRITE_SIZE 91MB, VGPR capped 64):
//   - NO __launch_bounds__ min-occupancy arg (r2-r4 compiled spill-free)
//   - NO long-lived register prefetch: staging is load->ds_write inside the
//     barrier pair; 16 waves/CU across 4 independent blocks hide the latency.
// MFMA layouts (measured m89/m91): A[m=l15][k=l4*8+j], B[k=l4*8+j][n=l15],
// C/D: col(n)=l15, row(m)=l4*4+reg.
// ---------------------------------------------------------------------------
#define GPAD   264   // sgT row stride (shorts): 2-way banks (free)
#define PROW   40    // sP row stride (shorts): 80 B, 16B-aligned
#define SOSTR  65    // sO row stride (floats): odd -> scattered banks

__global__ __launch_bounds__(256) void attn_k(
    const float* __restrict__ x,
    const unsigned short* __restrict__ thetaT,
    const unsigned short* __restrict__ phiT,
    const unsigned short* __restrict__ gcm,
    const float* __restrict__ Wo, const float* __restrict__ bo,
    const float* __restrict__ gammap,
    float* __restrict__ out)
{
    __shared__ unsigned short sphi[2][128][8];   // 4 KB   even/odd key split
    __shared__ unsigned short sgT[32][GPAD];     // 16.5 KB [c][m-chunk]
    __shared__ unsigned short sP[4][16][PROW];   // 5.1 KB  per-wave P slabs
    __shared__ float sO[32][SOSTR];              // 8.3 KB  [c][q] epilogue

    const int tid  = threadIdx.x;
    const int lane = tid & 63;
    const int wid  = tid >> 6;
    const int l15  = lane & 15;
    const int l4   = lane >> 4;

    const int b  = blockIdx.x >> 6;          // 64 blocks per batch
    const int q0 = (blockIdx.x & 63) << 6;   // 64 queries per block
    const int qw = q0 + wid * 16;            // this wave's 16 queries

    // theta A-fragment (K=8 real, rest zero): lanes 16..63 zero
    v8s aT;
    {
        v8s z = {};
        aT = z;
        if (l4 == 0)
            aT = *(const v8s*)(thetaT + ((size_t)b * N_ + qw + l15) * 8);
    }

    v4f accO[2];
    { v4f z = {}; accO[0] = z; accO[1] = z; }
    float lsum[4] = {0.f, 0.f, 0.f, 0.f};
    const v4f zf = {};

    const unsigned short* phb = phiT + (size_t)b * M_ * 8;
    const unsigned short* gb  = gcm  + (size_t)(b * 32) * M_;
    const int grow = tid >> 3, gch = tid & 7;

    for (int t = 0; t < 4; ++t) {            // 4 key tiles of 256
        __syncthreads();
        // stage phi tile (even/odd key split) + g tile [c][m]
        {
            const uint4 v = *(const uint4*)(phb + (size_t)(t * 256 + tid) * 8);
            *(uint4*)&sphi[tid & 1][tid >> 1][0] = v;
            const uint4* gs = (const uint4*)(gb + (size_t)grow * M_ + t * 256 + gch * 32);
            const uint4 g0 = gs[0], g1 = gs[1], g2 = gs[2], g3 = gs[3];
            uint4* gd = (uint4*)&sgT[grow][gch * 32];
            gd[0] = g0; gd[1] = g1; gd[2] = g2; gd[3] = g3;
        }
        __syncthreads();

        #pragma unroll
        for (int cc = 0; cc < 8; ++cc) {     // 32-key chunks
            v8s bph0, bph1;
            { v8s z = {}; bph0 = z; bph1 = z; }
            if (l4 == 0) {
                bph0 = *(const v8s*)&sphi[0][cc * 16 + l15][0];
                bph1 = *(const v8s*)&sphi[1][cc * 16 + l15][0];
            }
            v4f s0 = __builtin_amdgcn_mfma_f32_16x16x32_bf16(aT, bph0, zf, 0, 0, 0);
            v4f s1 = __builtin_amdgcn_mfma_f32_16x16x32_bf16(aT, bph1, zf, 0, 0, 0);
            #pragma unroll
            for (int r = 0; r < 4; ++r) {
                float e0 = __expf(s0[r]);    // key cc*32 + 2*l15
                float e1 = __expf(s1[r]);    // key cc*32 + 2*l15 + 1
                lsum[r] += e0 + e1;
                *(unsigned*)&sP[wid][l4 * 4 + r][2 * l15] = pack2bf(e0, e1);
            }
            v8s bg0 = *(const v8s*)&sgT[l15     ][cc * 32 + l4 * 8];
            v8s bg1 = *(const v8s*)&sgT[16 + l15][cc * 32 + l4 * 8];
            v8s ap  = *(const v8s*)&sP[wid][l15][l4 * 8];
            accO[0] = __builtin_amdgcn_mfma_f32_16x16x32_bf16(ap, bg0, accO[0], 0, 0, 0);
            accO[1] = __builtin_amdgcn_mfma_f32_16x16x32_bf16(ap, bg1, accO[1], 0, 0, 0);
        }
    }

    // softmax denominators: reduce across the 16 key-columns (lane&15)
    float rl[4];
    #pragma unroll
    for (int r = 0; r < 4; ++r) {
        float v = lsum[r];
        v += __shfl_xor(v, 1);
        v += __shfl_xor(v, 2);
        v += __shfl_xor(v, 4);
        v += __shfl_xor(v, 8);
        rl[r] = 1.0f / v;
    }

    // write normalized O to LDS [c][q_local]
    #pragma unroll
    for (int ct = 0; ct < 2; ++ct)
        #pragma unroll
        for (int r = 0; r < 4; ++r)
            sO[ct * 16 + l15][wid * 16 + l4 * 4 + r] = accO[ct][r] * rl[r];
    __syncthreads();

    // epilogue: out = gamma*(Wo . O + bo) + x. 256 thr = 64 q x 4 oc-quarters.
    {
        const int qq   = tid & 63;
        const int quad = tid >> 6;          // oc 16*quad .. 16*quad+15
        const int n    = q0 + qq;
        float col[32];
        #pragma unroll
        for (int c = 0; c < 32; ++c) col[c] = sO[c][qq];
        const float gamma = *gammap;
        const float* xb = x   + ((size_t)(b * 64 + quad * 16)) * N_ + n;
        float*       ob = out + ((size_t)(b * 64 + quad * 16)) * N_ + n;
        #pragma unroll
        for (int j = 0; j < 16; ++j) {
            const int oc = quad * 16 + j;
            const float* w = Wo + oc * 32;   // wave-uniform -> s_load
            float r = 0.f;
            #pragma unroll
            for (int c = 0; c < 32; ++c) r = fmaf(w[c], col[c], r);
            ob[(size_t)j * N_] = gamma * (r + bo[oc]) + xb[(size_t)j * N_];
        }
    }
}

// ---------------------------------------------------------------------------
extern "C" void kernel_launch(void* const* d_in, const int* in_sizes, int n_in,
                              void* d_out, int out_size, void* d_ws, size_t ws_size,
                              hipStream_t stream) {
    const float* x  = (const float*)d_in[0];
    const float* Wt = (const float*)d_in[1];
    const float* bt = (const float*)d_in[2];
    const float* Wp = (const float*)d_in[3];
    const float* bp = (const float*)d_in[4];
    const float* Wg = (const float*)d_in[5];
    const float* bg = (const float*)d_in[6];
    const float* Wo = (const float*)d_in[7];
    const float* bo = (const float*)d_in[8];
    const float* gm = (const float*)d_in[9];
    float* out = (float*)d_out;

    // workspace (bf16): thetaT [16][4096][8] | phiT [16][1024][8] | gcm [16][32][1024]
    unsigned short* thetaT = (unsigned short*)d_ws;
    unsigned short* phiT   = thetaT + (size_t)B_ * N_ * 8;
    unsigned short* gcm    = phiT   + (size_t)B_ * M_ * 8;

    hipLaunchKernelGGL(conv_pool_k, dim3(256), dim3(256), 0, stream,
                       x, Wt, bt, Wp, bp, Wg, bg, thetaT, phiT, gcm);
    hipLaunchKernelGGL(attn_k, dim3(1024), dim3(256), 0, stream,
                       x, thetaT, phiT, gcm, Wo, bo, gm, out);
}

// Round 7
// 121.432 us; speedup vs baseline: 1.1512x; 1.0173x over previous
//
#include <hip/hip_runtime.h>
#include <hip/hip_bf16.h>
#include <math.h>

#define B_ 16
#define C_ 64
#define N_ 4096   // 64*64 pixels
#define M_ 1024   // 32*32 pooled keys

typedef __attribute__((ext_vector_type(8))) short v8s;   // 8 bf16 (4 VGPRs)
typedef __attribute__((ext_vector_type(4))) float v4f;   // 4 fp32 acc

__device__ inline unsigned short f2bf(float f) {
    __hip_bfloat16 h = __float2bfloat16(f);
    return *(unsigned short*)&h;
}
__device__ inline unsigned pack2bf(float a, float b) {
    return (unsigned)f2bf(a) | ((unsigned)f2bf(b) << 16);
}
// single-instruction truncating pack: low16 = hi16(a), high16 = hi16(b)
__device__ inline unsigned packtrunc(float a, float b) {
    return __builtin_amdgcn_perm(__float_as_uint(b), __float_as_uint(a),
                                 0x07060302u);
}
__device__ inline v8s cvt8(float4 a, float4 b) {
    union { v8s v; unsigned u[4]; } r;
    r.u[0] = pack2bf(a.x, a.y);
    r.u[1] = pack2bf(a.z, a.w);
    r.u[2] = pack2bf(b.x, b.y);
    r.u[3] = pack2bf(b.z, b.w);
    return r.v;
}

// ---------------------------------------------------------------------------
// Kernel 1: MFMA conv (unchanged since round 4 — weights in A-fragments
// loaded once; wave = one image row; phi/g pooled via LDS epilogue).
// ---------------------------------------------------------------------------
#define SPSTR 268   // sPool row stride (floats): 2-way banks

__global__ __launch_bounds__(256) void conv_pool_k(
    const float* __restrict__ x,
    const float* __restrict__ Wt, const float* __restrict__ bt,
    const float* __restrict__ Wp, const float* __restrict__ bp,
    const float* __restrict__ Wg, const float* __restrict__ bg,
    unsigned short* __restrict__ thetaT,
    unsigned short* __restrict__ phiT,
    unsigned short* __restrict__ gcm)
{
    __shared__ float sPool[40 * SPSTR];   // ch 0..7 = phi, 8..39 = g

    const int tid  = threadIdx.x;
    const int lane = tid & 63;
    const int wid  = tid >> 6;
    const int l15  = lane & 15;
    const int l4   = lane >> 4;

    const int b  = blockIdx.x >> 4;
    const int y0 = (blockIdx.x & 15) << 2;
    const int y  = y0 + wid;

    const float* row0 = (l15 < 8) ? (Wt + l15 * 64) : (Wp + (l15 - 8) * 64);
    const float* row1 = Wg + l15 * 64;
    const float* row2 = Wg + (16 + l15) * 64;
    v8s afrag[3][2];
    #pragma unroll
    for (int kh = 0; kh < 2; ++kh) {
        const int c0 = kh * 32 + l4 * 8;
        afrag[0][kh] = cvt8(*(const float4*)(row0 + c0), *(const float4*)(row0 + c0 + 4));
        afrag[1][kh] = cvt8(*(const float4*)(row1 + c0), *(const float4*)(row1 + c0 + 4));
        afrag[2][kh] = cvt8(*(const float4*)(row2 + c0), *(const float4*)(row2 + c0 + 4));
    }

    v4f acc[4][3];
    {
        float bv[3][4];
        #pragma unroll
        for (int r = 0; r < 4; ++r) {
            const int o = l4 * 4 + r;
            bv[0][r] = (o < 8) ? bt[o] : bp[o - 8];
            bv[1][r] = bg[o];
            bv[2][r] = bg[16 + o];
        }
        #pragma unroll
        for (int nt = 0; nt < 4; ++nt)
            #pragma unroll
            for (int t = 0; t < 3; ++t) {
                v4f a; a[0] = bv[t][0]; a[1] = bv[t][1];
                a[2] = bv[t][2]; a[3] = bv[t][3];
                acc[nt][t] = a;
            }
    }

    const float* xb = x + (size_t)b * C_ * N_ + y * 64;
    #pragma unroll
    for (int nt = 0; nt < 4; ++nt) {
        const int n0 = nt * 16 + l15;
        #pragma unroll
        for (int kh = 0; kh < 2; ++kh) {
            const int cb = kh * 32 + l4 * 8;
            float f[8];
            #pragma unroll
            for (int j = 0; j < 8; ++j) f[j] = xb[(size_t)(cb + j) * N_ + n0];
            union { v8s v; unsigned u[4]; } bf;
            #pragma unroll
            for (int j = 0; j < 4; ++j) bf.u[j] = pack2bf(f[2*j], f[2*j+1]);
            #pragma unroll
            for (int t = 0; t < 3; ++t)
                acc[nt][t] = __builtin_amdgcn_mfma_f32_16x16x32_bf16(
                    afrag[t][kh], bf.v, acc[nt][t], 0, 0, 0);
        }
    }

    #pragma unroll
    for (int nt = 0; nt < 4; ++nt) {
        if (l4 < 2) {
            const int n = y * 64 + nt * 16 + l15;
            const unsigned lo = pack2bf(acc[nt][0][0], acc[nt][0][1]);
            const unsigned hi = pack2bf(acc[nt][0][2], acc[nt][0][3]);
            *(uint2*)(thetaT + ((size_t)b * N_ + n) * 8 + l4 * 4) = make_uint2(lo, hi);
        }
    }

    #pragma unroll
    for (int nt = 0; nt < 4; ++nt) {
        const int px = wid * 64 + nt * 16 + l15;
        if (l4 >= 2) {
            #pragma unroll
            for (int r = 0; r < 4; ++r)
                sPool[((l4 - 2) * 4 + r) * SPSTR + px] = acc[nt][0][r];
        }
        #pragma unroll
        for (int r = 0; r < 4; ++r) {
            sPool[(8  + l4 * 4 + r) * SPSTR + px] = acc[nt][1][r];
            sPool[(24 + l4 * 4 + r) * SPSTR + px] = acc[nt][2][r];
        }
    }
    __syncthreads();

    {
        const int pm  = tid & 63, grp = tid >> 6;
        const int pr  = pm >> 5, pc = pm & 31;
        const int p00 = pr * 128 + pc * 2;
        const int mg  = ((y0 >> 1) + pr) * 32 + pc;
        #pragma unroll
        for (int i = 0; i < 10; ++i) {
            const int ch = grp * 10 + i;
            const float* sp = sPool + ch * SPSTR;
            const float v = fmaxf(fmaxf(sp[p00], sp[p00 + 1]),
                                  fmaxf(sp[p00 + 64], sp[p00 + 65]));
            if (ch < 8) phiT[((size_t)b * M_ + mg) * 8 + ch] = f2bf(v);
            else        gcm[((size_t)(b * 32 + ch - 8)) * M_ + mg] = f2bf(v);
        }
    }
}

// ---------------------------------------------------------------------------
// Kernel 2 (round 7): MFMA flash attention, de-phase-locked.
// r6 evidence: 8->16 waves/CU changed nothing (40 -> 42 us); pipes ran
// serialized (VALU 27% + LDS ~35% + MFMA 5%, none saturated) because every
// wave executes the same serial chain in barrier-locked phase. Fixes:
//  (1) per-wave chunk rotation (exp-sum is order-invariant) -> co-resident
//      waves permanently phase-staggered, cross-wave pipe overlap;
//  (2) pair-wise pipelining: 2 chunks' S-phases batched before their
//      O-phases -> 2x independent work per chain step; bg reads hoisted;
//  (3) single-instruction v_perm truncating pack for P (was 5-instr RNE)
//      -> VALU phase ~40% smaller;
//  (4) transposed sO epilogue ([q][c], b128 reads).
// MFMA layouts (measured m89/m91): A[m=l15][k=l4*8+j], B[k=l4*8+j][n=l15],
// C/D: col(n)=l15, row(m)=l4*4+reg.
// ---------------------------------------------------------------------------
#define GPAD   264   // sgT row stride (shorts): 2-way banks (free)
#define PROW   40    // sP row stride (shorts): 80 B, 16B-aligned, 2-way banks
#define SOSTR  36    // sO row stride (floats): 144 B, 16B-aligned

__global__ __launch_bounds__(256) void attn_k(
    const float* __restrict__ x,
    const unsigned short* __restrict__ thetaT,
    const unsigned short* __restrict__ phiT,
    const unsigned short* __restrict__ gcm,
    const float* __restrict__ Wo, const float* __restrict__ bo,
    const float* __restrict__ gammap,
    float* __restrict__ out)
{
    __shared__ unsigned short sphi[2][128][8];     // 4 KB   even/odd key split
    __shared__ unsigned short sgT[32][GPAD];       // 16.5 KB [c][m-chunk]
    __shared__ unsigned short sP[4][2][16][PROW];  // 10.2 KB per-wave, 2 slabs
    __shared__ float sO[64][SOSTR];                // 9.2 KB  [q][c] epilogue

    const int tid  = threadIdx.x;
    const int lane = tid & 63;
    const int wid  = tid >> 6;
    const int l15  = lane & 15;
    const int l4   = lane >> 4;

    const int b  = blockIdx.x >> 6;          // 64 blocks per batch
    const int q0 = (blockIdx.x & 63) << 6;   // 64 queries per block
    const int qw = q0 + wid * 16;            // this wave's 16 queries

    // phase-stagger: even rotation of the 8 chunks, differs across the 4
    // waves of a block AND across co-resident blocks on a CU
    const int rot = ((wid + blockIdx.x) << 1) & 7;

    // theta A-fragment (K=8 real, rest zero): lanes 16..63 zero
    v8s aT;
    {
        v8s z = {};
        aT = z;
        if (l4 == 0)
            aT = *(const v8s*)(thetaT + ((size_t)b * N_ + qw + l15) * 8);
    }

    v4f accO[2];
    { v4f z = {}; accO[0] = z; accO[1] = z; }
    float lsum[4] = {0.f, 0.f, 0.f, 0.f};
    const v4f zf = {};

    const unsigned short* phb = phiT + (size_t)b * M_ * 8;
    const unsigned short* gb  = gcm  + (size_t)(b * 32) * M_;
    const int grow = tid >> 3, gch = tid & 7;

    for (int t = 0; t < 4; ++t) {            // 4 key tiles of 256
        __syncthreads();
        // stage phi tile (even/odd key split) + g tile [c][m]
        {
            const uint4 v = *(const uint4*)(phb + (size_t)(t * 256 + tid) * 8);
            *(uint4*)&sphi[tid & 1][tid >> 1][0] = v;
            const uint4* gs = (const uint4*)(gb + (size_t)grow * M_ + t * 256 + gch * 32);
            const uint4 g0 = gs[0], g1 = gs[1], g2 = gs[2], g3 = gs[3];
            uint4* gd = (uint4*)&sgT[grow][gch * 32];
            gd[0] = g0; gd[1] = g1; gd[2] = g2; gd[3] = g3;
        }
        __syncthreads();

        for (int pp = 0; pp < 4; ++pp) {     // 4 pairs of 32-key chunks
            const int ca = (rot + 2 * pp) & 7;   // even chunk id
            const int cb = ca + 1;               // odd partner, same tile

            // --- S phase for both chunks (4 independent MFMAs)
            v8s bphA0, bphA1, bphB0, bphB1;
            { v8s z = {}; bphA0 = z; bphA1 = z; bphB0 = z; bphB1 = z; }
            if (l4 == 0) {
                bphA0 = *(const v8s*)&sphi[0][ca * 16 + l15][0];
                bphA1 = *(const v8s*)&sphi[1][ca * 16 + l15][0];
                bphB0 = *(const v8s*)&sphi[0][cb * 16 + l15][0];
                bphB1 = *(const v8s*)&sphi[1][cb * 16 + l15][0];
            }
            v4f sA0 = __builtin_amdgcn_mfma_f32_16x16x32_bf16(aT, bphA0, zf, 0, 0, 0);
            v4f sA1 = __builtin_amdgcn_mfma_f32_16x16x32_bf16(aT, bphA1, zf, 0, 0, 0);
            v4f sB0 = __builtin_amdgcn_mfma_f32_16x16x32_bf16(aT, bphB0, zf, 0, 0, 0);
            v4f sB1 = __builtin_amdgcn_mfma_f32_16x16x32_bf16(aT, bphB1, zf, 0, 0, 0);

            // --- bg reads: independent of S/exp, issue early
            v8s bgA0 = *(const v8s*)&sgT[l15     ][ca * 32 + l4 * 8];
            v8s bgA1 = *(const v8s*)&sgT[16 + l15][ca * 32 + l4 * 8];
            v8s bgB0 = *(const v8s*)&sgT[l15     ][cb * 32 + l4 * 8];
            v8s bgB1 = *(const v8s*)&sgT[16 + l15][cb * 32 + l4 * 8];

            // --- exp + 1-instr truncating pack + lsum
            #pragma unroll
            for (int r = 0; r < 4; ++r) {
                const float a0 = __expf(sA0[r]);   // key ca*32 + 2*l15
                const float a1 = __expf(sA1[r]);   // key ca*32 + 2*l15+1
                const float b0 = __expf(sB0[r]);
                const float b1 = __expf(sB1[r]);
                lsum[r] += (a0 + a1) + (b0 + b1);
                *(unsigned*)&sP[wid][0][l4 * 4 + r][2 * l15] = packtrunc(a0, a1);
                *(unsigned*)&sP[wid][1][l4 * 4 + r][2 * l15] = packtrunc(b0, b1);
            }

            // --- O phase for both chunks
            v8s apA = *(const v8s*)&sP[wid][0][l15][l4 * 8];
            v8s apB = *(const v8s*)&sP[wid][1][l15][l4 * 8];
            accO[0] = __builtin_amdgcn_mfma_f32_16x16x32_bf16(apA, bgA0, accO[0], 0, 0, 0);
            accO[1] = __builtin_amdgcn_mfma_f32_16x16x32_bf16(apA, bgA1, accO[1], 0, 0, 0);
            accO[0] = __builtin_amdgcn_mfma_f32_16x16x32_bf16(apB, bgB0, accO[0], 0, 0, 0);
            accO[1] = __builtin_amdgcn_mfma_f32_16x16x32_bf16(apB, bgB1, accO[1], 0, 0, 0);
        }
    }

    // softmax denominators: reduce across the 16 key-columns (lane&15)
    float rl[4];
    #pragma unroll
    for (int r = 0; r < 4; ++r) {
        float v = lsum[r];
        v += __shfl_xor(v, 1);
        v += __shfl_xor(v, 2);
        v += __shfl_xor(v, 4);
        v += __shfl_xor(v, 8);
        rl[r] = 1.0f / v;
    }

    // write normalized O to LDS [q][c]  (row 16B-aligned for b128 reads)
    #pragma unroll
    for (int ct = 0; ct < 2; ++ct)
        #pragma unroll
        for (int r = 0; r < 4; ++r)
            sO[wid * 16 + l4 * 4 + r][ct * 16 + l15] = accO[ct][r] * rl[r];
    __syncthreads();

    // epilogue: out = gamma*(Wo . O + bo) + x. 256 thr = 64 q x 4 oc-quarters.
    {
        const int qq   = tid & 63;
        const int quad = tid >> 6;          // oc 16*quad .. 16*quad+15
        const int n    = q0 + qq;
        float4 col4[8];
        const float4* so4 = (const float4*)&sO[qq][0];
        #pragma unroll
        for (int j = 0; j < 8; ++j) col4[j] = so4[j];
        const float* col = (const float*)col4;
        const float gamma = *gammap;
        const float* xb = x   + ((size_t)(b * 64 + quad * 16)) * N_ + n;
        float*       ob = out + ((size_t)(b * 64 + quad * 16)) * N_ + n;
        #pragma unroll
        for (int j = 0; j < 16; ++j) {
            const int oc = quad * 16 + j;
            const float* w = Wo + oc * 32;   // wave-uniform -> s_load
            float r = 0.f;
            #pragma unroll
            for (int c = 0; c < 32; ++c) r = fmaf(w[c], col[c], r);
            ob[(size_t)j * N_] = gamma * (r + bo[oc]) + xb[(size_t)j * N_];
        }
    }
}

// ---------------------------------------------------------------------------
extern "C" void kernel_launch(void* const* d_in, const int* in_sizes, int n_in,
                              void* d_out, int out_size, void* d_ws, size_t ws_size,
                              hipStream_t stream) {
    const float* x  = (const float*)d_in[0];
    const float* Wt = (const float*)d_in[1];
    const float* bt = (const float*)d_in[2];
    const float* Wp = (const float*)d_in[3];
    const float* bp = (const float*)d_in[4];
    const float* Wg = (const float*)d_in[5];
    const float* bg = (const float*)d_in[6];
    const float* Wo = (const float*)d_in[7];
    const float* bo = (const float*)d_in[8];
    const float* gm = (const float*)d_in[9];
    float* out = (float*)d_out;

    // workspace (bf16): thetaT [16][4096][8] | phiT [16][1024][8] | gcm [16][32][1024]
    unsigned short* thetaT = (unsigned short*)d_ws;
    unsigned short* phiT   = thetaT + (size_t)B_ * N_ * 8;
    unsigned short* gcm    = phiT   + (size_t)B_ * M_ * 8;

    hipLaunchKernelGGL(conv_pool_k, dim3(256), dim3(256), 0, stream,
                       x, Wt, bt, Wp, bp, Wg, bg, thetaT, phiT, gcm);
    hipLaunchKernelGGL(attn_k, dim3(1024), dim3(256), 0, stream,
                       x, thetaT, phiT, gcm, Wo, bo, gm, out);
}